// Round 2
// baseline (177.621 us; speedup 1.0000x reference)
//
#include <hip/hip_runtime.h>
#include <hip/hip_bf16.h>
#include <stdint.h>

// Problem constants
#define B_   8
#define S_   2047
#define L_   2048      // S+1 (CLS prepended)
#define H_   256       // HIDDEN
#define NH_  8
#define HD_  32
#define V_   32001     // VOCAB+1

__device__ __forceinline__ float b2f(unsigned short u) {
    union { uint32_t i; float f; } c; c.i = ((uint32_t)u) << 16; return c.f;
}
__device__ __forceinline__ unsigned short f2b(float f) {
    union { float f; uint32_t i; } c; c.f = f;
    uint32_t x = c.i;
    uint32_t r = (x + 0x7fffu + ((x >> 16) & 1u)) >> 16;
    return (unsigned short)r;
}

// ---------------------------------------------------------------------------
// K0: 1 block. y0 = emb[2]+pe[0]; q0[n][k] = wq[n,k,:]·y0;
//     qk[n][h] = (sum_k q0[n][k]*wk[n,k,h]) / sqrt(32). Also zero ybar.
// ---------------------------------------------------------------------------
__global__ __launch_bounds__(256) void k0_prep(const float* __restrict__ emb,
                                               const float* __restrict__ wq,
                                               const float* __restrict__ wk,
                                               float* __restrict__ qk,
                                               float* __restrict__ y0,
                                               float* __restrict__ ybar) {
    __shared__ float y0_l[H_];
    __shared__ float q0_l[NH_ * HD_];
    int tid = threadIdx.x;
    // pe[0][h] = sin(0)=0 (even h), cos(0)=1 (odd h)
    float v = emb[2 * H_ + tid] + ((tid & 1) ? 1.0f : 0.0f);
    y0_l[tid] = v;
    y0[tid] = v;
    __syncthreads();
    {   // q0: thread = (n,k)
        const float* w = wq + tid * H_;
        float acc = 0.f;
        for (int h = 0; h < H_; ++h) acc += w[h] * y0_l[h];
        q0_l[tid] = acc;
    }
    __syncthreads();
    const float inv_sqrt = 0.17677669529663687f;  // 1/sqrt(32)
    for (int n = 0; n < NH_; ++n) {
        float acc = 0.f;
        for (int k = 0; k < HD_; ++k)
            acc += q0_l[n * HD_ + k] * wk[(n * HD_ + k) * H_ + tid];
        qk[n * H_ + tid] = acc * inv_sqrt;
    }
    for (int i = tid; i < B_ * NH_ * H_; i += 256) ybar[i] = 0.0f;
}

// ---------------------------------------------------------------------------
// K1: one wave per t (2048 waves). Computes y[b,t,:] (cached as bf16) and
//     scores[b,n,t] = qk[n]·y[b,t] for all 8 b, 8 n.
// ---------------------------------------------------------------------------
__global__ __launch_bounds__(256) void k1_scores(const int* __restrict__ x,
                                                 const float* __restrict__ emb,
                                                 const float* __restrict__ qkw,
                                                 unsigned short* __restrict__ ycache,
                                                 float* __restrict__ scores) {
    int tid  = threadIdx.x;
    int lane = tid & 63;
    int t    = blockIdx.x * 4 + (tid >> 6);   // 0..2047
    int h0   = lane * 4;

    float qr[NH_][4];
#pragma unroll
    for (int n = 0; n < NH_; ++n)
        *(float4*)(&qr[n][0]) = *(const float4*)(qkw + n * H_ + h0);

    // pe: h0 covers pairs (2i,2i+1) for i = lane*2 and lane*2+1
    const float cdiv = 0.07195578414202881f;  // ln(10000)/128
    float div0 = expf(-(float)(lane * 2) * cdiv);
    float div1 = expf(-(float)(lane * 2 + 1) * cdiv);
    float a0 = (float)t * div0, a1 = (float)t * div1;
    float s0 = sinf(a0), c0 = cosf(a0), s1 = sinf(a1), c1 = cosf(a1);

    for (int b = 0; b < B_; ++b) {
        int tok = (t == 0) ? 2 : x[b * S_ + t - 1];
        float4 ev = *(const float4*)(emb + tok * H_ + h0);
        float y0v = ev.x + s0;
        float y1v = ev.y + c0;
        float y2v = ev.z + s1;
        float y3v = ev.w + c1;
        ushort4 st;
        st.x = f2b(y0v); st.y = f2b(y1v); st.z = f2b(y2v); st.w = f2b(y3v);
        *(ushort4*)(ycache + ((b * L_ + t) << 8) + h0) = st;

        float acc[NH_];
#pragma unroll
        for (int n = 0; n < NH_; ++n)
            acc[n] = qr[n][0] * y0v + qr[n][1] * y1v + qr[n][2] * y2v + qr[n][3] * y3v;
#pragma unroll
        for (int off = 32; off > 0; off >>= 1) {
#pragma unroll
            for (int n = 0; n < NH_; ++n)
                acc[n] += __shfl_xor(acc[n], off, 64);
        }
        if (lane == 0) {
            float* sp = scores + (b * NH_) * L_ + t;
#pragma unroll
            for (int n = 0; n < NH_; ++n) sp[n * L_] = acc[n];
        }
    }
}

// ---------------------------------------------------------------------------
// K2: softmax over t per (b,n) row; writes transposed P: Pt[b][t][n].
// ---------------------------------------------------------------------------
__global__ __launch_bounds__(256) void k2_softmax(const float* __restrict__ scores,
                                                  float* __restrict__ Pt) {
    int bn = blockIdx.x;          // 0..63
    int b = bn >> 3, n = bn & 7;
    int tid = threadIdx.x, lane = tid & 63, w = tid >> 6;
    const float* row = scores + bn * L_;
    float s[8];
#pragma unroll
    for (int k = 0; k < 8; ++k) s[k] = row[k * 256 + tid];
    float m = s[0];
#pragma unroll
    for (int k = 1; k < 8; ++k) m = fmaxf(m, s[k]);
#pragma unroll
    for (int off = 32; off > 0; off >>= 1) m = fmaxf(m, __shfl_xor(m, off, 64));
    __shared__ float red[8];
    if (lane == 0) red[w] = m;
    __syncthreads();
    float M = fmaxf(fmaxf(red[0], red[1]), fmaxf(red[2], red[3]));
    float e[8], sum = 0.f;
#pragma unroll
    for (int k = 0; k < 8; ++k) { e[k] = __expf(s[k] - M); sum += e[k]; }
#pragma unroll
    for (int off = 32; off > 0; off >>= 1) sum += __shfl_xor(sum, off, 64);
    if (lane == 0) red[4 + w] = sum;
    __syncthreads();
    float inv = 1.0f / (red[4] + red[5] + red[6] + red[7]);
#pragma unroll
    for (int k = 0; k < 8; ++k) {
        int t = k * 256 + tid;
        Pt[(b * L_ + t) * NH_ + n] = e[k] * inv;
    }
}

// ---------------------------------------------------------------------------
// K3: ybar[b,n,h] = sum_t P[b,n,t]*y[b,t,h]. Block = (b, chunk of 64 t).
// ---------------------------------------------------------------------------
__global__ __launch_bounds__(256) void k3_ybar(const float* __restrict__ Pt,
                                               const unsigned short* __restrict__ ycache,
                                               float* __restrict__ ybar) {
    int b = blockIdx.x >> 5, chunk = blockIdx.x & 31;  // 32 chunks x 64 t
    int t0 = chunk * 64;
    int tid = threadIdx.x;
    __shared__ float p_l[64 * NH_];
    for (int i = tid; i < 64 * NH_; i += 256)
        p_l[i] = Pt[(b * L_ + t0) * NH_ + i];
    __syncthreads();
    float acc[NH_] = {0.f, 0.f, 0.f, 0.f, 0.f, 0.f, 0.f, 0.f};
    const unsigned short* yc = ycache + (b * L_ + t0) * H_ + tid;
    for (int tt = 0; tt < 64; ++tt) {
        float yv = b2f(yc[tt * H_]);
#pragma unroll
        for (int n = 0; n < NH_; ++n) acc[n] += p_l[tt * NH_ + n] * yv;
    }
#pragma unroll
    for (int n = 0; n < NH_; ++n)
        atomicAdd(ybar + (b * NH_ + n) * H_ + tid, acc[n]);
}

// ---------------------------------------------------------------------------
// K4: per b: o[n,k] = wv[n,k,:]·ybar[b,n,:]; z[b,i] = wo[i,:]·o + 2*y0[i]
// ---------------------------------------------------------------------------
__global__ __launch_bounds__(256) void k4_proj(const float* __restrict__ ybar,
                                               const float* __restrict__ wv,
                                               const float* __restrict__ wo,
                                               const float* __restrict__ y0,
                                               float* __restrict__ z) {
    int b = blockIdx.x, tid = threadIdx.x;
    __shared__ float yb_l[NH_ * H_];
    __shared__ float o_l[NH_ * HD_];
    for (int i = tid; i < NH_ * H_; i += 256) yb_l[i] = ybar[b * NH_ * H_ + i];
    __syncthreads();
    {   // thread = (n,k) = tid; o index j = n*32+k = tid
        int n = tid >> 5;
        const float* w = wv + tid * H_;
        float acc = 0.f;
        for (int h = 0; h < H_; ++h) acc += w[h] * yb_l[n * H_ + h];
        o_l[tid] = acc;
    }
    __syncthreads();
    {
        const float* w = wo + tid * H_;
        float acc = 0.f;
        for (int j = 0; j < NH_ * HD_; ++j) acc += w[j] * o_l[j];
        z[b * H_ + tid] = acc + 2.0f * y0[tid];
    }
}

// ---------------------------------------------------------------------------
// K5: out[b,v] = z[b,:]·wu[v,:]. One wave per 16 consecutive v; block covers
//     64 consecutive v, stages results in LDS, coalesced store.
// ---------------------------------------------------------------------------
__global__ __launch_bounds__(256) void k5_out(const float* __restrict__ z,
                                              const float* __restrict__ wu,
                                              float* __restrict__ out) {
    int tid = threadIdx.x, lane = tid & 63, w = tid >> 6;
    int h0 = lane * 4;
    float zr[B_][4];
#pragma unroll
    for (int b = 0; b < B_; ++b)
        *(float4*)(&zr[b][0]) = *(const float4*)(z + b * H_ + h0);
    __shared__ float o_l[B_ * 64];
    int base = blockIdx.x * 64;
    int v0 = base + w * 16;
    for (int i = 0; i < 16; ++i) {
        int v = v0 + i;
        float acc[B_] = {0.f, 0.f, 0.f, 0.f, 0.f, 0.f, 0.f, 0.f};
        if (v < V_) {
            float4 wv4 = *(const float4*)(wu + v * H_ + h0);
#pragma unroll
            for (int b = 0; b < B_; ++b)
                acc[b] = zr[b][0] * wv4.x + zr[b][1] * wv4.y + zr[b][2] * wv4.z + zr[b][3] * wv4.w;
        }
#pragma unroll
        for (int off = 32; off > 0; off >>= 1) {
#pragma unroll
            for (int b = 0; b < B_; ++b) acc[b] += __shfl_xor(acc[b], off, 64);
        }
        if (lane == 0) {
            int vl = w * 16 + i;
#pragma unroll
            for (int b = 0; b < B_; ++b) o_l[b * 64 + vl] = acc[b];
        }
    }
    __syncthreads();
    for (int i = tid; i < B_ * 64; i += 256) {
        int b = i >> 6, vl = i & 63;
        int v = base + vl;
        if (v < V_) out[b * V_ + v] = o_l[i];
    }
}

// ---------------------------------------------------------------------------
extern "C" void kernel_launch(void* const* d_in, const int* in_sizes, int n_in,
                              void* d_out, int out_size, void* d_ws, size_t ws_size,
                              hipStream_t stream) {
    const int*   x   = (const int*)d_in[0];
    const float* emb = (const float*)d_in[1];
    const float* wq  = (const float*)d_in[2];
    const float* wk  = (const float*)d_in[3];
    const float* wv  = (const float*)d_in[4];
    const float* wo  = (const float*)d_in[5];
    const float* wu  = (const float*)d_in[6];
    float*       out = (float*)d_out;

    // ws layout (floats unless noted):
    // qk[2048] | y0[256] | z[2048] | ybar[16384] | Pt[131072] | scores[131072]
    // | ycache (bf16, 8*2048*256 ushort) — total ~9.1 MiB
    float* qk     = (float*)d_ws;
    float* y0     = qk + NH_ * H_;
    float* z      = y0 + H_;
    float* ybar   = z + B_ * H_;
    float* Pt     = ybar + B_ * NH_ * H_;
    float* scores = Pt + B_ * L_ * NH_;
    unsigned short* ycache = (unsigned short*)(scores + B_ * NH_ * L_);

    k0_prep   <<<1,   256, 0, stream>>>(emb, wq, wk, qk, y0, ybar);
    k1_scores <<<512, 256, 0, stream>>>(x, emb, qk, ycache, scores);
    k2_softmax<<<64,  256, 0, stream>>>(scores, Pt);
    k3_ybar   <<<256, 256, 0, stream>>>(Pt, ycache, ybar);
    k4_proj   <<<8,   256, 0, stream>>>(ybar, wv, wo, y0, z);
    k5_out    <<<(V_ + 63) / 64, 256, 0, stream>>>(z, wu, out);
}